// Round 2
// baseline (435.051 us; speedup 1.0000x reference)
//
#include <hip/hip_runtime.h>
#include <math.h>

// Sizes fixed by the problem.
#define N_AG   512
#define HIDD   256
#define OBSD   128
// P = 512*511/2 = 130816 pairs, out = [P,3]

__device__ __forceinline__ void fma4(float4& acc, float4 a, float4 b){
    acc.x += a.x*b.x; acc.y += a.y*b.y; acc.z += a.z*b.z; acc.w += a.w*b.w;
}
__device__ __forceinline__ float hsum(float4 a){ return (a.x+a.y)+(a.z+a.w); }

// ---------------- K1: fused fc1 + qkv, 4 agents per block, grid 128 ----------------
__global__ __launch_bounds__(256) void k_embed(const float* __restrict__ in,
        const float* __restrict__ w1, const float* __restrict__ b1,
        const float* __restrict__ wq, const float* __restrict__ bq,
        float* __restrict__ hid, float* __restrict__ qkv){
    __shared__ float lin[4*OBSD];
    __shared__ float lh[4*HIDD];
    int at = blockIdx.x, t = threadIdx.x;
    if (t < 128) ((float4*)lin)[t] = ((const float4*)(in + at*4*OBSD))[t];
    __syncthreads();
    int ol = t & 63, g = t >> 6;           // g = agent within block (1 per wave)
    const float4* x4 = (const float4*)(lin + g*OBSD);
    #pragma unroll
    for (int ot = 0; ot < 4; ++ot){
        int o = ot*64 + ol;
        const float4* w4 = (const float4*)(w1 + o*OBSD);
        float4 acc = {0,0,0,0};
        #pragma unroll
        for (int c = 0; c < OBSD/4; ++c) fma4(acc, x4[c], w4[c]);
        float h = fmaxf(hsum(acc) + b1[o], 0.f);
        lh[g*HIDD + o] = h;
        hid[(at*4+g)*HIDD + o] = h;
    }
    __syncthreads();
    const float4* h4 = (const float4*)(lh + g*HIDD);
    #pragma unroll 2
    for (int ot = 0; ot < 12; ++ot){
        int o = ot*64 + ol;                // 0..767
        const float4* w4 = (const float4*)(wq + o*HIDD);
        float4 acc = {0,0,0,0};
        #pragma unroll 16
        for (int c = 0; c < HIDD/4; ++c) fma4(acc, h4[c], w4[c]);
        qkv[(at*4+g)*768 + o] = hsum(acc) + bq[o];
    }
}

// ---------------- K2: attention (blocks 0..511, 1 row each) || value-head stream (blocks 512..2559) ----------------
__global__ __launch_bounds__(256) void k_attn_vpart(const float* __restrict__ qkv,
        const float* __restrict__ ow, const float* __restrict__ ob,
        const float* __restrict__ hid, const float* __restrict__ vw,
        float* __restrict__ hout, float* __restrict__ partial){
    int t = threadIdx.x;
    if (blockIdx.x >= N_AG){
        // ---- vpart: stream 64KB chunk of one vfc2_w row, dot with flattened hid ----
        int id = blockIdx.x - N_AG;        // 0..2047
        int chunk = id & 7, o = id >> 3;
        const float4* h4 = (const float4*)hid;
        const float4* w4 = (const float4*)vw;
        long base  = (long)chunk*4096;     // float4 units
        long wbase = (long)o*32768 + base;
        float4 acc4 = {0,0,0,0};
        #pragma unroll 4
        for (int it = 0; it < 16; ++it)
            fma4(acc4, h4[base + it*256 + t], w4[wbase + it*256 + t]);
        float acc = hsum(acc4);
        for (int off = 32; off; off >>= 1) acc += __shfl_xor(acc, off);
        __shared__ float redv[4];
        int lane = t & 63, wid = t >> 6;
        if (lane == 0) redv[wid] = acc;
        __syncthreads();
        if (t == 0) partial[o*8 + chunk] = redv[0]+redv[1]+redv[2]+redv[3];
        return;
    }
    // ---- attention, one query row per block ----
    int r = blockIdx.x;
    __shared__ float q[HIDD];
    __shared__ float sc[512];
    __shared__ float av[HIDD];
    __shared__ float red2[8];
    if (t < 64) ((float4*)q)[t] = ((const float4*)(qkv + r*768))[t];
    __syncthreads();
    const float4* q4 = (const float4*)q;
    #pragma unroll
    for (int jj = 0; jj < 2; ++jj){
        int j = t + jj*256;
        const float4* k4 = (const float4*)(qkv + j*768 + HIDD);
        float4 acc = {0,0,0,0};
        #pragma unroll 16
        for (int c = 0; c < HIDD/4; ++c) fma4(acc, q4[c], k4[c]);
        sc[j] = hsum(acc) * 0.0625f;       // 1/sqrt(256)
    }
    __syncthreads();
    int lane = t & 63, wid = t >> 6;
    float s0 = sc[t], s1 = sc[t+256];
    float m = fmaxf(s0, s1);
    for (int off = 32; off; off >>= 1) m = fmaxf(m, __shfl_xor(m, off));
    if (lane == 0) red2[wid] = m;
    __syncthreads();
    m = fmaxf(fmaxf(red2[0],red2[1]), fmaxf(red2[2],red2[3]));
    float e0 = expf(s0-m), e1 = expf(s1-m);
    float s = e0 + e1;
    for (int off = 32; off; off >>= 1) s += __shfl_xor(s, off);
    if (lane == 0) red2[4+wid] = s;
    __syncthreads();
    float inv = 1.f/(red2[4]+red2[5]+red2[6]+red2[7]);
    sc[t] = e0*inv; sc[t+256] = e1*inv;
    __syncthreads();
    // av = attn_row @ V (V reads coalesced across t; unroll for load ILP)
    float acc = 0.f;
    #pragma unroll 8
    for (int j = 0; j < 512; ++j) acc += sc[j]*qkv[j*768 + 512 + t];
    av[t] = acc;
    __syncthreads();
    // h = av @ out_proj_w.T + ob
    const float4* a4 = (const float4*)av;
    const float4* w4 = (const float4*)(ow + t*HIDD);
    float4 acc4 = {0,0,0,0};
    #pragma unroll 16
    for (int c = 0; c < HIDD/4; ++c) fma4(acc4, a4[c], w4[c]);
    hout[r*HIDD + t] = hsum(acc4) + ob[t];
}

// ---------------- K3: A/B projections (blocks 0..511) || value finish (block 512) ----------------
__global__ __launch_bounds__(256) void k_ab_value(const float* __restrict__ hin,
        const float* __restrict__ w2, const float* __restrict__ b2,
        const float* __restrict__ partial, const float* __restrict__ vb,
        const float* __restrict__ v3w, const float* __restrict__ v3b,
        float* __restrict__ A, float* __restrict__ B, float* __restrict__ value){
    int t = threadIdx.x;
    if (blockIdx.x == 512){
        float s = vb[t];
        #pragma unroll
        for (int c = 0; c < 8; ++c) s += partial[t*8 + c];
        s = fmaxf(s, 0.f) * v3w[t];
        for (int off = 32; off; off >>= 1) s += __shfl_xor(s, off);
        __shared__ float redv[4];
        int lane = t & 63, wid = t >> 6;
        if (lane == 0) redv[wid] = s;
        __syncthreads();
        if (t == 0) value[0] = redv[0]+redv[1]+redv[2]+redv[3] + v3b[0];
        return;
    }
    __shared__ float lin[8*HIDD];
    int id = blockIdx.x, at = id >> 3, ot = id & 7;
    const float4* in4 = (const float4*)(hin + at*8*HIDD);
    ((float4*)lin)[t]       = in4[t];
    ((float4*)lin)[t + 256] = in4[t + 256];
    __syncthreads();
    int ol = t & 63, g = t >> 6;
    int o2 = ot*64 + ol;                   // 0..511
    bool isA = o2 < HIDD;
    int o = isA ? o2 : o2 - HIDD;
    const float4* w4 = (const float4*)(w2 + o*512 + (isA ? 0 : HIDD));
    const float4* la = (const float4*)(lin + (g*2)*HIDD);
    const float4* lb = (const float4*)(lin + (g*2+1)*HIDD);
    float4 acc0 = {0,0,0,0}, acc1 = {0,0,0,0};
    #pragma unroll 16
    for (int c = 0; c < HIDD/4; ++c){
        float4 wv = w4[c];
        fma4(acc0, la[c], wv);
        fma4(acc1, lb[c], wv);
    }
    int a0 = at*8 + g*2;
    float* dst = isA ? A : B;
    float bb = isA ? b2[o] : 0.f;          // fold fc2_b into A
    dst[a0*HIDD + o]     = hsum(acc0) + bb;
    dst[(a0+1)*HIDD + o] = hsum(acc1) + bb;
}

// ---------------- K4: per-pair x=relu(A[i]+B[j]); out = [sigmoid(wd.x+bd), 1-., value] ----------------
// LDS stride 260 floats (mod 32 = 4 -> only 2-way bank alias, free)
__global__ __launch_bounds__(256) void k_pairs(const float* __restrict__ A,
        const float* __restrict__ B, const float* __restrict__ w3,
        const float* __restrict__ b3, const float* __restrict__ value,
        float* __restrict__ out){
    int ti = blockIdx.x, tj = blockIdx.y;
    if (tj < ti) return;                   // strictly-lower tiles have no pairs
    __shared__ float la[16*260], lb[16*260], lw[256];
    int t = threadIdx.x;
    #pragma unroll
    for (int l = 0; l < 4; ++l){
        int idx = l*256 + t;
        int r = idx >> 6, c4 = idx & 63;
        ((float4*)la)[r*65 + c4] = ((const float4*)A)[(ti*16 + r)*64 + c4];
        ((float4*)lb)[r*65 + c4] = ((const float4*)B)[(tj*16 + r)*64 + c4];
    }
    lw[t] = w3[t] - w3[256 + t];           // fc3_w[0]-fc3_w[1]
    __syncthreads();
    float val = value[0];
    float bd  = b3[0] - b3[1];
    int il = t >> 4, jl = t & 15;
    int i = ti*16 + il, j = tj*16 + jl;
    if (j > i){
        const float4* a4 = (const float4*)(la + il*260);
        const float4* b4 = (const float4*)(lb + jl*260);
        const float4* w4 = (const float4*)lw;
        float4 acc = {0,0,0,0};
        #pragma unroll 8
        for (int c = 0; c < 64; ++c){
            float4 aa = a4[c], bb = b4[c], wv = w4[c];
            acc.x += fmaxf(aa.x + bb.x, 0.f)*wv.x;
            acc.y += fmaxf(aa.y + bb.y, 0.f)*wv.y;
            acc.z += fmaxf(aa.z + bb.z, 0.f)*wv.z;
            acc.w += fmaxf(aa.w + bb.w, 0.f)*wv.w;
        }
        float z = hsum(acc) + bd;
        float o0 = 1.f/(1.f + expf(-z));
        int p = i*511 - (i*(i-1))/2 + (j - i - 1);
        out[3*p]   = o0;
        out[3*p+1] = 1.f - o0;
        out[3*p+2] = val;
    }
}

extern "C" void kernel_launch(void* const* d_in, const int* in_sizes, int n_in,
                              void* d_out, int out_size, void* d_ws, size_t ws_size,
                              hipStream_t stream){
    const float* inputs = (const float*)d_in[0];
    const float* fc1_w  = (const float*)d_in[1];
    const float* fc1_b  = (const float*)d_in[2];
    const float* inp_w  = (const float*)d_in[3];
    const float* inp_b  = (const float*)d_in[4];
    const float* outp_w = (const float*)d_in[5];
    const float* outp_b = (const float*)d_in[6];
    const float* fc2_w  = (const float*)d_in[7];
    const float* fc2_b  = (const float*)d_in[8];
    const float* fc3_w  = (const float*)d_in[9];
    const float* fc3_b  = (const float*)d_in[10];
    const float* vfc2_w = (const float*)d_in[11];
    const float* vfc2_b = (const float*)d_in[12];
    const float* vfc3_w = (const float*)d_in[13];
    const float* vfc3_b = (const float*)d_in[14];
    float* out = (float*)d_out;
    float* ws  = (float*)d_ws;
    // ws layout (floats): total ~920k (~3.7 MB)
    float* hid     = ws;             // 512*256
    float* qkv     = ws + 131072;    // 512*768
    float* h       = ws + 524288;    // 512*256
    float* A       = ws + 655360;    // 512*256
    float* B       = ws + 786432;    // 512*256
    float* partial = ws + 917504;    // 256*8
    float* value   = ws + 919552;    // 1

    k_embed     <<<dim3(128),       256, 0, stream>>>(inputs, fc1_w, fc1_b, inp_w, inp_b, hid, qkv);
    k_attn_vpart<<<dim3(2560),      256, 0, stream>>>(qkv, outp_w, outp_b, hid, vfc2_w, h, partial);
    k_ab_value  <<<dim3(513),       256, 0, stream>>>(h, fc2_w, fc2_b, partial, vfc2_b, vfc3_w, vfc3_b, A, B, value);
    k_pairs     <<<dim3(32, 32),    256, 0, stream>>>(A, B, fc3_w, fc3_b, value, out);
}

// Round 3
// 314.240 us; speedup vs baseline: 1.3845x; 1.3845x over previous
//
#include <hip/hip_runtime.h>
#include <math.h>

// Sizes fixed by the problem.
#define N_AG   512
#define HIDD   256
#define OBSD   128
// P = 512*511/2 = 130816 pairs, out = [P,3]

__device__ __forceinline__ void fma4(float4& acc, float4 a, float4 b){
    acc.x += a.x*b.x; acc.y += a.y*b.y; acc.z += a.z*b.z; acc.w += a.w*b.w;
}
__device__ __forceinline__ float hsum(float4 a){ return (a.x+a.y)+(a.z+a.w); }

// ---------------- K1: hid = relu(inputs @ fc1_w.T + fc1_b) ----------------
// grid (4 out-tiles of 64, 64 agent-tiles of 8), 256 threads  [round-1 structure: parallelism wins]
__global__ __launch_bounds__(256) void k_fc1(const float* __restrict__ in,
        const float* __restrict__ w, const float* __restrict__ b,
        float* __restrict__ hid){
    __shared__ float lin[8*OBSD];
    int at = blockIdx.y, ot = blockIdx.x, t = threadIdx.x;
    ((float4*)lin)[t] = ((const float4*)(in + at*8*OBSD))[t];
    __syncthreads();
    int ol = t & 63, g = t >> 6;
    int o = ot*64 + ol;
    const float4* w4 = (const float4*)(w + o*OBSD);
    const float4* la = (const float4*)(lin + (g*2)*OBSD);
    const float4* lb = (const float4*)(lin + (g*2+1)*OBSD);
    float4 a0 = {0,0,0,0}, a1 = {0,0,0,0};
    #pragma unroll
    for (int c = 0; c < OBSD/4; ++c){
        float4 wv = w4[c];
        fma4(a0, la[c], wv);
        fma4(a1, lb[c], wv);
    }
    float bb = b[o];
    int ag = at*8 + g*2;
    hid[ag*HIDD + o]     = fmaxf(hsum(a0) + bb, 0.f);
    hid[(ag+1)*HIDD + o] = fmaxf(hsum(a1) + bb, 0.f);
}

// ---------------- K2: qkv = hid @ in_proj_w.T + in_proj_b ----------------
// grid (12 out-tiles of 64, 64 agent-tiles of 8), 256 threads
__global__ __launch_bounds__(256) void k_qkv(const float* __restrict__ hid,
        const float* __restrict__ w, const float* __restrict__ b,
        float* __restrict__ qkv){
    __shared__ float lin[8*HIDD];
    int at = blockIdx.y, ot = blockIdx.x, t = threadIdx.x;
    const float4* in4 = (const float4*)(hid + at*8*HIDD);
    ((float4*)lin)[t]       = in4[t];
    ((float4*)lin)[t + 256] = in4[t + 256];
    __syncthreads();
    int ol = t & 63, g = t >> 6;
    int o = ot*64 + ol;                       // 0..767
    const float4* w4 = (const float4*)(w + o*HIDD);
    const float4* la = (const float4*)(lin + (g*2)*HIDD);
    const float4* lb = (const float4*)(lin + (g*2+1)*HIDD);
    float4 a0 = {0,0,0,0}, a1 = {0,0,0,0};
    #pragma unroll 16
    for (int c = 0; c < HIDD/4; ++c){
        float4 wv = w4[c];
        fma4(a0, la[c], wv);
        fma4(a1, lb[c], wv);
    }
    float bb = b[o];
    int ag = at*8 + g*2;
    qkv[ag*768 + o]     = hsum(a0) + bb;
    qkv[(ag+1)*768 + o] = hsum(a1) + bb;
}

// ---------------- K3: attention 2 rows/block (blocks 0..255) || vfc2_w stream (blocks 256..2303) ----------------
__global__ __launch_bounds__(256) void k_attn_vpart(const float* __restrict__ qkv,
        const float* __restrict__ ow, const float* __restrict__ ob,
        const float* __restrict__ hid, const float* __restrict__ vw,
        float* __restrict__ hout, float* __restrict__ partial){
    int t = threadIdx.x;
    if (blockIdx.x >= 256){
        // ---- vpart: 64KB chunk of one vfc2_w row, dot with flattened hid ----
        int id = blockIdx.x - 256;         // 0..2047
        int chunk = id & 7, o = id >> 3;
        const float4* h4 = (const float4*)hid;
        const float4* w4 = (const float4*)vw;
        long base  = (long)chunk*4096;     // float4 units
        long wbase = (long)o*32768 + base;
        float4 acc4 = {0,0,0,0};
        #pragma unroll 4
        for (int it = 0; it < 16; ++it)
            fma4(acc4, h4[base + it*256 + t], w4[wbase + it*256 + t]);
        float acc = hsum(acc4);
        for (int off = 32; off; off >>= 1) acc += __shfl_xor(acc, off);
        __shared__ float redv[4];
        int lane = t & 63, wid = t >> 6;
        if (lane == 0) redv[wid] = acc;
        __syncthreads();
        if (t == 0) partial[o*8 + chunk] = redv[0]+redv[1]+redv[2]+redv[3];
        return;
    }
    // ---- attention, two query rows per block (halves K/V L2 re-reads) ----
    int r0 = blockIdx.x*2;
    __shared__ float q2[2*HIDD];
    __shared__ float sc[2*512];
    __shared__ float av[2*HIDD];
    __shared__ float red[16];
    if (t < 128){
        int r = t >> 6, c4 = t & 63;
        ((float4*)q2)[r*64 + c4] = ((const float4*)(qkv + (r0+r)*768))[c4];
    }
    __syncthreads();
    const float4* qa = (const float4*)q2;
    const float4* qb = (const float4*)(q2 + HIDD);
    #pragma unroll
    for (int jj = 0; jj < 2; ++jj){
        int j = t + jj*256;
        const float4* k4 = (const float4*)(qkv + j*768 + HIDD);
        float4 acc0 = {0,0,0,0}, acc1 = {0,0,0,0};
        #pragma unroll 16
        for (int c = 0; c < HIDD/4; ++c){
            float4 kv = k4[c];
            fma4(acc0, qa[c], kv);
            fma4(acc1, qb[c], kv);
        }
        sc[j]       = hsum(acc0) * 0.0625f;   // 1/sqrt(256)
        sc[512 + j] = hsum(acc1) * 0.0625f;
    }
    __syncthreads();
    int lane = t & 63, wid = t >> 6;
    float s00 = sc[t], s01 = sc[t+256], s10 = sc[512+t], s11 = sc[512+t+256];
    float m0 = fmaxf(s00, s01), m1 = fmaxf(s10, s11);
    for (int off = 32; off; off >>= 1){
        m0 = fmaxf(m0, __shfl_xor(m0, off));
        m1 = fmaxf(m1, __shfl_xor(m1, off));
    }
    if (lane == 0){ red[wid] = m0; red[4+wid] = m1; }
    __syncthreads();
    m0 = fmaxf(fmaxf(red[0],red[1]), fmaxf(red[2],red[3]));
    m1 = fmaxf(fmaxf(red[4],red[5]), fmaxf(red[6],red[7]));
    float e00 = expf(s00-m0), e01 = expf(s01-m0), e10 = expf(s10-m1), e11 = expf(s11-m1);
    float t0 = e00+e01, t1 = e10+e11;
    for (int off = 32; off; off >>= 1){ t0 += __shfl_xor(t0, off); t1 += __shfl_xor(t1, off); }
    if (lane == 0){ red[8+wid] = t0; red[12+wid] = t1; }
    __syncthreads();
    float inv0 = 1.f/(red[8]+red[9]+red[10]+red[11]);
    float inv1 = 1.f/(red[12]+red[13]+red[14]+red[15]);
    sc[t] = e00*inv0; sc[t+256] = e01*inv0;
    sc[512+t] = e10*inv1; sc[512+t+256] = e11*inv1;
    __syncthreads();
    // av = attn @ v (coalesced across t; both rows share the V read)
    {
        float acc0 = 0.f, acc1 = 0.f;
        #pragma unroll 8
        for (int j = 0; j < 512; ++j){
            float vv = qkv[j*768 + 512 + t];
            acc0 += sc[j]*vv;
            acc1 += sc[512+j]*vv;
        }
        av[t] = acc0; av[HIDD+t] = acc1;
    }
    __syncthreads();
    // h = av @ out_proj_w.T + ob
    {
        const float4* w4 = (const float4*)(ow + t*HIDD);
        const float4* a4 = (const float4*)av;
        const float4* b4 = (const float4*)(av + HIDD);
        float4 h0 = {0,0,0,0}, h1 = {0,0,0,0};
        #pragma unroll 16
        for (int c = 0; c < HIDD/4; ++c){
            float4 wv = w4[c];
            fma4(h0, a4[c], wv);
            fma4(h1, b4[c], wv);
        }
        float bb = ob[t];
        hout[r0*HIDD + t]     = hsum(h0) + bb;
        hout[(r0+1)*HIDD + t] = hsum(h1) + bb;
    }
}

// ---------------- K4: A/B projections (blocks 0..511) || value finish (block 512) ----------------
__global__ __launch_bounds__(256) void k_ab_value(const float* __restrict__ hin,
        const float* __restrict__ w2, const float* __restrict__ b2,
        const float* __restrict__ partial, const float* __restrict__ vb,
        const float* __restrict__ v3w, const float* __restrict__ v3b,
        float* __restrict__ A, float* __restrict__ B, float* __restrict__ value){
    int t = threadIdx.x;
    if (blockIdx.x == 512){
        float s = vb[t];
        #pragma unroll
        for (int c = 0; c < 8; ++c) s += partial[t*8 + c];
        s = fmaxf(s, 0.f) * v3w[t];
        for (int off = 32; off; off >>= 1) s += __shfl_xor(s, off);
        __shared__ float redv[4];
        int lane = t & 63, wid = t >> 6;
        if (lane == 0) redv[wid] = s;
        __syncthreads();
        if (t == 0) value[0] = redv[0]+redv[1]+redv[2]+redv[3] + v3b[0];
        return;
    }
    __shared__ float lin[8*HIDD];
    int id = blockIdx.x, at = id >> 3, ot = id & 7;
    const float4* in4 = (const float4*)(hin + at*8*HIDD);
    ((float4*)lin)[t]       = in4[t];
    ((float4*)lin)[t + 256] = in4[t + 256];
    __syncthreads();
    int ol = t & 63, g = t >> 6;
    int o2 = ot*64 + ol;                   // 0..511
    bool isA = o2 < HIDD;
    int o = isA ? o2 : o2 - HIDD;
    const float4* w4 = (const float4*)(w2 + o*512 + (isA ? 0 : HIDD));
    const float4* la = (const float4*)(lin + (g*2)*HIDD);
    const float4* lb = (const float4*)(lin + (g*2+1)*HIDD);
    float4 acc0 = {0,0,0,0}, acc1 = {0,0,0,0};
    #pragma unroll 16
    for (int c = 0; c < HIDD/4; ++c){
        float4 wv = w4[c];
        fma4(acc0, la[c], wv);
        fma4(acc1, lb[c], wv);
    }
    int a0 = at*8 + g*2;
    float* dst = isA ? A : B;
    float bb = isA ? b2[o] : 0.f;          // fold fc2_b into A
    dst[a0*HIDD + o]     = hsum(acc0) + bb;
    dst[(a0+1)*HIDD + o] = hsum(acc1) + bb;
}

// ---------------- K5: per-pair x=relu(A[i]+B[j]); out = [sigmoid(wd.x+bd), 1-., value] ----------------
// LDS stride 260 floats (mod 32 = 4 -> only 2-way bank alias, free)
__global__ __launch_bounds__(256) void k_pairs(const float* __restrict__ A,
        const float* __restrict__ B, const float* __restrict__ w3,
        const float* __restrict__ b3, const float* __restrict__ value,
        float* __restrict__ out){
    int ti = blockIdx.x, tj = blockIdx.y;
    if (tj < ti) return;                   // strictly-lower tiles have no pairs
    __shared__ float la[16*260], lb[16*260], lw[256];
    int t = threadIdx.x;
    #pragma unroll
    for (int l = 0; l < 4; ++l){
        int idx = l*256 + t;
        int r = idx >> 6, c4 = idx & 63;
        ((float4*)la)[r*65 + c4] = ((const float4*)A)[(ti*16 + r)*64 + c4];
        ((float4*)lb)[r*65 + c4] = ((const float4*)B)[(tj*16 + r)*64 + c4];
    }
    lw[t] = w3[t] - w3[256 + t];           // fc3_w[0]-fc3_w[1]
    __syncthreads();
    float val = value[0];
    float bd  = b3[0] - b3[1];
    int il = t >> 4, jl = t & 15;
    int i = ti*16 + il, j = tj*16 + jl;
    if (j > i){
        const float4* a4 = (const float4*)(la + il*260);
        const float4* b4 = (const float4*)(lb + jl*260);
        const float4* w4 = (const float4*)lw;
        float4 acc = {0,0,0,0};
        #pragma unroll 8
        for (int c = 0; c < 64; ++c){
            float4 aa = a4[c], bb = b4[c], wv = w4[c];
            acc.x += fmaxf(aa.x + bb.x, 0.f)*wv.x;
            acc.y += fmaxf(aa.y + bb.y, 0.f)*wv.y;
            acc.z += fmaxf(aa.z + bb.z, 0.f)*wv.z;
            acc.w += fmaxf(aa.w + bb.w, 0.f)*wv.w;
        }
        float z = hsum(acc) + bd;
        float o0 = 1.f/(1.f + expf(-z));
        int p = i*511 - (i*(i-1))/2 + (j - i - 1);
        out[3*p]   = o0;
        out[3*p+1] = 1.f - o0;
        out[3*p+2] = val;
    }
}

extern "C" void kernel_launch(void* const* d_in, const int* in_sizes, int n_in,
                              void* d_out, int out_size, void* d_ws, size_t ws_size,
                              hipStream_t stream){
    const float* inputs = (const float*)d_in[0];
    const float* fc1_w  = (const float*)d_in[1];
    const float* fc1_b  = (const float*)d_in[2];
    const float* inp_w  = (const float*)d_in[3];
    const float* inp_b  = (const float*)d_in[4];
    const float* outp_w = (const float*)d_in[5];
    const float* outp_b = (const float*)d_in[6];
    const float* fc2_w  = (const float*)d_in[7];
    const float* fc2_b  = (const float*)d_in[8];
    const float* fc3_w  = (const float*)d_in[9];
    const float* fc3_b  = (const float*)d_in[10];
    const float* vfc2_w = (const float*)d_in[11];
    const float* vfc2_b = (const float*)d_in[12];
    const float* vfc3_w = (const float*)d_in[13];
    const float* vfc3_b = (const float*)d_in[14];
    float* out = (float*)d_out;
    float* ws  = (float*)d_ws;
    // ws layout (floats): total ~920k (~3.7 MB)
    float* hid     = ws;             // 512*256
    float* qkv     = ws + 131072;    // 512*768
    float* h       = ws + 524288;    // 512*256
    float* A       = ws + 655360;    // 512*256
    float* B       = ws + 786432;    // 512*256
    float* partial = ws + 917504;    // 256*8
    float* value   = ws + 919552;    // 1

    k_fc1       <<<dim3(4, 64),  256, 0, stream>>>(inputs, fc1_w, fc1_b, hid);
    k_qkv       <<<dim3(12, 64), 256, 0, stream>>>(hid, inp_w, inp_b, qkv);
    k_attn_vpart<<<dim3(2304),   256, 0, stream>>>(qkv, outp_w, outp_b, hid, vfc2_w, h, partial);
    k_ab_value  <<<dim3(513),    256, 0, stream>>>(h, fc2_w, fc2_b, partial, vfc2_b, vfc3_w, vfc3_b, A, B, value);
    k_pairs     <<<dim3(32, 32), 256, 0, stream>>>(A, B, fc3_w, fc3_b, value, out);
}

// Round 4
// 304.766 us; speedup vs baseline: 1.4275x; 1.0311x over previous
//
#include <hip/hip_runtime.h>
#include <math.h>

// Sizes fixed by the problem.
#define N_AG   512
#define HIDD   256
#define OBSD   128
// P = 512*511/2 = 130816 pairs, out = [P,3]

__device__ __forceinline__ void fma4(float4& acc, float4 a, float4 b){
    acc.x += a.x*b.x; acc.y += a.y*b.y; acc.z += a.z*b.z; acc.w += a.w*b.w;
}
__device__ __forceinline__ float hsum(float4 a){ return (a.x+a.y)+(a.z+a.w); }

// ---------------- K1: hid = relu(inputs @ fc1_w.T + fc1_b) ----------------
__global__ __launch_bounds__(256, 2) void k_fc1(const float* __restrict__ in,
        const float* __restrict__ w, const float* __restrict__ b,
        float* __restrict__ hid){
    __shared__ float lin[8*OBSD];
    int at = blockIdx.y, ot = blockIdx.x, t = threadIdx.x;
    ((float4*)lin)[t] = ((const float4*)(in + at*8*OBSD))[t];
    __syncthreads();
    int ol = t & 63, g = t >> 6;
    int o = ot*64 + ol;
    const float4* w4 = (const float4*)(w + o*OBSD);
    const float4* la = (const float4*)(lin + (g*2)*OBSD);
    const float4* lb = (const float4*)(lin + (g*2+1)*OBSD);
    float4 a0 = {0,0,0,0}, a1 = {0,0,0,0};
    #pragma unroll
    for (int c = 0; c < OBSD/4; ++c){
        float4 wv = w4[c];
        fma4(a0, la[c], wv);
        fma4(a1, lb[c], wv);
    }
    float bb = b[o];
    int ag = at*8 + g*2;
    hid[ag*HIDD + o]     = fmaxf(hsum(a0) + bb, 0.f);
    hid[(ag+1)*HIDD + o] = fmaxf(hsum(a1) + bb, 0.f);
}

// ---------------- K2: qkv = hid @ in_proj_w.T + in_proj_b ----------------
__global__ __launch_bounds__(256, 2) void k_qkv(const float* __restrict__ hid,
        const float* __restrict__ w, const float* __restrict__ b,
        float* __restrict__ qkv){
    __shared__ float lin[8*HIDD];
    int at = blockIdx.y, ot = blockIdx.x, t = threadIdx.x;
    const float4* in4 = (const float4*)(hid + at*8*HIDD);
    ((float4*)lin)[t]       = in4[t];
    ((float4*)lin)[t + 256] = in4[t + 256];
    __syncthreads();
    int ol = t & 63, g = t >> 6;
    int o = ot*64 + ol;                       // 0..767
    const float4* w4 = (const float4*)(w + o*HIDD);
    const float4* la = (const float4*)(lin + (g*2)*HIDD);
    const float4* lb = (const float4*)(lin + (g*2+1)*HIDD);
    float4 a0 = {0,0,0,0}, a1 = {0,0,0,0};
    #pragma unroll 8
    for (int c = 0; c < HIDD/4; ++c){
        float4 wv = w4[c];
        fma4(a0, la[c], wv);
        fma4(a1, lb[c], wv);
    }
    float bb = b[o];
    int ag = at*8 + g*2;
    qkv[ag*768 + o]     = hsum(a0) + bb;
    qkv[(ag+1)*768 + o] = hsum(a1) + bb;
}

// ---------------- K3: attention 4 rows/block (blocks 0..127) || vfc2_w stream (blocks 128..2175) ----------------
__global__ __launch_bounds__(256, 2) void k_attn_vpart(const float* __restrict__ qkv,
        const float* __restrict__ ow, const float* __restrict__ ob,
        const float* __restrict__ hid, const float* __restrict__ vw,
        float* __restrict__ hout, float* __restrict__ partial){
    int t = threadIdx.x;
    if (blockIdx.x >= 128){
        // ---- vpart: 64KB chunk of one vfc2_w row, dot with flattened hid ----
        int id = blockIdx.x - 128;         // 0..2047
        int chunk = id & 7, o = id >> 3;
        const float4* h4 = (const float4*)hid;
        const float4* w4 = (const float4*)vw;
        long base  = (long)chunk*4096;     // float4 units
        long wbase = (long)o*32768 + base;
        float4 aa = {0,0,0,0}, ab = {0,0,0,0};
        #pragma unroll 4
        for (int it = 0; it < 8; ++it){    // two interleaved streams -> 2x load ILP
            fma4(aa, h4[base + it*256 + t],       w4[wbase + it*256 + t]);
            fma4(ab, h4[base + (it+8)*256 + t],   w4[wbase + (it+8)*256 + t]);
        }
        float acc = hsum(aa) + hsum(ab);
        for (int off = 32; off; off >>= 1) acc += __shfl_xor(acc, off);
        __shared__ float redv[4];
        int lane = t & 63, wid = t >> 6;
        if (lane == 0) redv[wid] = acc;
        __syncthreads();
        if (t == 0) partial[o*8 + chunk] = redv[0]+redv[1]+redv[2]+redv[3];
        return;
    }
    // ---- attention, four query rows per block ----
    int r0 = blockIdx.x*4;
    __shared__ float qs[4*HIDD];     // 4 KB
    __shared__ float sc[4*512];      // 8 KB
    __shared__ float av[4*HIDD];     // 4 KB
    {   // load 4 Q rows (1024 floats = 256 float4, one per thread)
        int r = t >> 6, c4 = t & 63;
        ((float4*)qs)[t] = ((const float4*)(qkv + (r0+r)*768))[c4];
    }
    __syncthreads();
    const float4* q0 = (const float4*)qs;
    const float4* q1 = (const float4*)(qs + HIDD);
    const float4* q2 = (const float4*)(qs + 2*HIDD);
    const float4* q3 = (const float4*)(qs + 3*HIDD);
    // scores: each thread handles keys j=t and j=t+256; 4 independent row-chains
    #pragma unroll
    for (int jj = 0; jj < 2; ++jj){
        int j = t + jj*256;
        const float4* k4 = (const float4*)(qkv + j*768 + HIDD);
        float4 a0 = {0,0,0,0}, a1 = {0,0,0,0}, a2 = {0,0,0,0}, a3 = {0,0,0,0};
        #pragma unroll 8
        for (int c = 0; c < HIDD/4; ++c){
            float4 kv = k4[c];
            fma4(a0, q0[c], kv);
            fma4(a1, q1[c], kv);
            fma4(a2, q2[c], kv);
            fma4(a3, q3[c], kv);
        }
        sc[j]        = hsum(a0) * 0.0625f;   // 1/sqrt(256)
        sc[512 + j]  = hsum(a1) * 0.0625f;
        sc[1024 + j] = hsum(a2) * 0.0625f;
        sc[1536 + j] = hsum(a3) * 0.0625f;
    }
    __syncthreads();
    // softmax: one wave per row
    {
        int wv = t >> 6, ln = t & 63;
        float* row = sc + wv*512;
        float vals[8];
        float m = -1e30f;
        #pragma unroll
        for (int k = 0; k < 8; ++k){ vals[k] = row[ln + k*64]; m = fmaxf(m, vals[k]); }
        for (int off = 32; off; off >>= 1) m = fmaxf(m, __shfl_xor(m, off));
        float s = 0.f;
        #pragma unroll
        for (int k = 0; k < 8; ++k){ vals[k] = expf(vals[k] - m); s += vals[k]; }
        for (int off = 32; off; off >>= 1) s += __shfl_xor(s, off);
        float inv = 1.f / s;
        #pragma unroll
        for (int k = 0; k < 8; ++k) row[ln + k*64] = vals[k]*inv;
    }
    __syncthreads();
    // av = attn @ V: thread owns dim d=t, 4 row accumulators; V loads coalesced
    {
        float4 p = {0,0,0,0};
        #pragma unroll 8
        for (int j = 0; j < 512; ++j){
            float vv = qkv[j*768 + 512 + t];
            p.x += sc[j]*vv;
            p.y += sc[512+j]*vv;
            p.z += sc[1024+j]*vv;
            p.w += sc[1536+j]*vv;
        }
        av[t] = p.x; av[HIDD+t] = p.y; av[2*HIDD+t] = p.z; av[3*HIDD+t] = p.w;
    }
    __syncthreads();
    // h = av @ out_proj_w.T + ob
    {
        const float4* w4 = (const float4*)(ow + t*HIDD);
        const float4* a0 = (const float4*)av;
        const float4* a1 = (const float4*)(av + HIDD);
        const float4* a2 = (const float4*)(av + 2*HIDD);
        const float4* a3 = (const float4*)(av + 3*HIDD);
        float4 h0 = {0,0,0,0}, h1 = {0,0,0,0}, h2 = {0,0,0,0}, h3 = {0,0,0,0};
        #pragma unroll 8
        for (int c = 0; c < HIDD/4; ++c){
            float4 wv = w4[c];
            fma4(h0, a0[c], wv);
            fma4(h1, a1[c], wv);
            fma4(h2, a2[c], wv);
            fma4(h3, a3[c], wv);
        }
        float bb = ob[t];
        hout[r0*HIDD + t]       = hsum(h0) + bb;
        hout[(r0+1)*HIDD + t]   = hsum(h1) + bb;
        hout[(r0+2)*HIDD + t]   = hsum(h2) + bb;
        hout[(r0+3)*HIDD + t]   = hsum(h3) + bb;
    }
}

// ---------------- K4: A/B projections (blocks 0..511) || value finish (block 512) ----------------
__global__ __launch_bounds__(256, 2) void k_ab_value(const float* __restrict__ hin,
        const float* __restrict__ w2, const float* __restrict__ b2,
        const float* __restrict__ partial, const float* __restrict__ vb,
        const float* __restrict__ v3w, const float* __restrict__ v3b,
        float* __restrict__ A, float* __restrict__ B, float* __restrict__ value){
    int t = threadIdx.x;
    if (blockIdx.x == 512){
        float s = vb[t];
        #pragma unroll
        for (int c = 0; c < 8; ++c) s += partial[t*8 + c];
        s = fmaxf(s, 0.f) * v3w[t];
        for (int off = 32; off; off >>= 1) s += __shfl_xor(s, off);
        __shared__ float redv[4];
        int lane = t & 63, wid = t >> 6;
        if (lane == 0) redv[wid] = s;
        __syncthreads();
        if (t == 0) value[0] = redv[0]+redv[1]+redv[2]+redv[3] + v3b[0];
        return;
    }
    __shared__ float lin[8*HIDD];
    int id = blockIdx.x, at = id >> 3, ot = id & 7;
    const float4* in4 = (const float4*)(hin + at*8*HIDD);
    ((float4*)lin)[t]       = in4[t];
    ((float4*)lin)[t + 256] = in4[t + 256];
    __syncthreads();
    int ol = t & 63, g = t >> 6;
    int o2 = ot*64 + ol;                   // 0..511
    bool isA = o2 < HIDD;
    int o = isA ? o2 : o2 - HIDD;
    const float4* w4 = (const float4*)(w2 + o*512 + (isA ? 0 : HIDD));
    const float4* la = (const float4*)(lin + (g*2)*HIDD);
    const float4* lb = (const float4*)(lin + (g*2+1)*HIDD);
    float4 acc0 = {0,0,0,0}, acc1 = {0,0,0,0};
    #pragma unroll 8
    for (int c = 0; c < HIDD/4; ++c){
        float4 wv = w4[c];
        fma4(acc0, la[c], wv);
        fma4(acc1, lb[c], wv);
    }
    int a0 = at*8 + g*2;
    float* dst = isA ? A : B;
    float bb = isA ? b2[o] : 0.f;          // fold fc2_b into A
    dst[a0*HIDD + o]     = hsum(acc0) + bb;
    dst[(a0+1)*HIDD + o] = hsum(acc1) + bb;
}

// ---------------- K5: per-pair x=relu(A[i]+B[j]); out = [sigmoid(wd.x+bd), 1-., value] ----------------
__global__ __launch_bounds__(256, 2) void k_pairs(const float* __restrict__ A,
        const float* __restrict__ B, const float* __restrict__ w3,
        const float* __restrict__ b3, const float* __restrict__ value,
        float* __restrict__ out){
    int ti = blockIdx.x, tj = blockIdx.y;
    if (tj < ti) return;                   // strictly-lower tiles have no pairs
    __shared__ float la[16*260], lb[16*260], lw[256];
    int t = threadIdx.x;
    #pragma unroll
    for (int l = 0; l < 4; ++l){
        int idx = l*256 + t;
        int r = idx >> 6, c4 = idx & 63;
        ((float4*)la)[r*65 + c4] = ((const float4*)A)[(ti*16 + r)*64 + c4];
        ((float4*)lb)[r*65 + c4] = ((const float4*)B)[(tj*16 + r)*64 + c4];
    }
    lw[t] = w3[t] - w3[256 + t];           // fc3_w[0]-fc3_w[1]
    __syncthreads();
    float val = value[0];
    float bd  = b3[0] - b3[1];
    int il = t >> 4, jl = t & 15;
    int i = ti*16 + il, j = tj*16 + jl;
    if (j > i){
        const float4* a4 = (const float4*)(la + il*260);
        const float4* b4 = (const float4*)(lb + jl*260);
        const float4* w4 = (const float4*)lw;
        float4 acc = {0,0,0,0};
        #pragma unroll 8
        for (int c = 0; c < 64; ++c){
            float4 aa = a4[c], bb = b4[c], wv = w4[c];
            acc.x += fmaxf(aa.x + bb.x, 0.f)*wv.x;
            acc.y += fmaxf(aa.y + bb.y, 0.f)*wv.y;
            acc.z += fmaxf(aa.z + bb.z, 0.f)*wv.z;
            acc.w += fmaxf(aa.w + bb.w, 0.f)*wv.w;
        }
        float z = hsum(acc) + bd;
        float o0 = 1.f/(1.f + expf(-z));
        int p = i*511 - (i*(i-1))/2 + (j - i - 1);
        out[3*p]   = o0;
        out[3*p+1] = 1.f - o0;
        out[3*p+2] = val;
    }
}

extern "C" void kernel_launch(void* const* d_in, const int* in_sizes, int n_in,
                              void* d_out, int out_size, void* d_ws, size_t ws_size,
                              hipStream_t stream){
    const float* inputs = (const float*)d_in[0];
    const float* fc1_w  = (const float*)d_in[1];
    const float* fc1_b  = (const float*)d_in[2];
    const float* inp_w  = (const float*)d_in[3];
    const float* inp_b  = (const float*)d_in[4];
    const float* outp_w = (const float*)d_in[5];
    const float* outp_b = (const float*)d_in[6];
    const float* fc2_w  = (const float*)d_in[7];
    const float* fc2_b  = (const float*)d_in[8];
    const float* fc3_w  = (const float*)d_in[9];
    const float* fc3_b  = (const float*)d_in[10];
    const float* vfc2_w = (const float*)d_in[11];
    const float* vfc2_b = (const float*)d_in[12];
    const float* vfc3_w = (const float*)d_in[13];
    const float* vfc3_b = (const float*)d_in[14];
    float* out = (float*)d_out;
    float* ws  = (float*)d_ws;
    // ws layout (floats): total ~920k (~3.7 MB)
    float* hid     = ws;             // 512*256
    float* qkv     = ws + 131072;    // 512*768
    float* h       = ws + 524288;    // 512*256
    float* A       = ws + 655360;    // 512*256
    float* B       = ws + 786432;    // 512*256
    float* partial = ws + 917504;    // 256*8
    float* value   = ws + 919552;    // 1

    k_fc1       <<<dim3(4, 64),  256, 0, stream>>>(inputs, fc1_w, fc1_b, hid);
    k_qkv       <<<dim3(12, 64), 256, 0, stream>>>(hid, inp_w, inp_b, qkv);
    k_attn_vpart<<<dim3(2176),   256, 0, stream>>>(qkv, outp_w, outp_b, hid, vfc2_w, h, partial);
    k_ab_value  <<<dim3(513),    256, 0, stream>>>(h, fc2_w, fc2_b, partial, vfc2_b, vfc3_w, vfc3_b, A, B, value);
    k_pairs     <<<dim3(32, 32), 256, 0, stream>>>(A, B, fc3_w, fc3_b, value, out);
}

// Round 5
// 299.267 us; speedup vs baseline: 1.4537x; 1.0184x over previous
//
#include <hip/hip_runtime.h>
#include <math.h>

// Sizes fixed by the problem.
#define N_AG   512
#define HIDD   256
#define OBSD   128
// P = 512*511/2 = 130816 pairs, out = [P,3]

__device__ __forceinline__ void fma4(float4& acc, float4 a, float4 b){
    acc.x += a.x*b.x; acc.y += a.y*b.y; acc.z += a.z*b.z; acc.w += a.w*b.w;
}
__device__ __forceinline__ float hsum(float4 a){ return (a.x+a.y)+(a.z+a.w); }

// ---- shared GEMM-tile helpers: 64x64 output tile, K-chunks of 32, LDS [32][68] kk-major ----
// stage transposed: dst[kk][row] = src[(row0+row)*stride + colbase + kk], kk in [0,32)
__device__ __forceinline__ void stage_rows(float* dst, const float* __restrict__ src,
        int row0, int stride, int colbase, int t){
    #pragma unroll
    for (int half = 0; half < 2; ++half){
        int idx = half*256 + t;
        int row = idx >> 3, c4 = idx & 7;
        float4 v = *(const float4*)(src + (row0+row)*stride + colbase + c4*4);
        dst[(c4*4+0)*68 + row] = v.x;
        dst[(c4*4+1)*68 + row] = v.y;
        dst[(c4*4+2)*68 + row] = v.z;
        dst[(c4*4+3)*68 + row] = v.w;
    }
}
// acc[r] = row r of the thread's 4x4 patch (float4 across 4 cols)
__device__ __forceinline__ void tile_compute(const float* As, const float* Bs,
        int tx, int ty, float4 acc[4]){
    #pragma unroll
    for (int kk = 0; kk < 32; ++kk){
        float4 a = *(const float4*)(As + kk*68 + ty*4);
        float4 b = *(const float4*)(Bs + kk*68 + tx*4);
        acc[0].x += a.x*b.x; acc[0].y += a.x*b.y; acc[0].z += a.x*b.z; acc[0].w += a.x*b.w;
        acc[1].x += a.y*b.x; acc[1].y += a.y*b.y; acc[1].z += a.y*b.z; acc[1].w += a.y*b.w;
        acc[2].x += a.z*b.x; acc[2].y += a.z*b.y; acc[2].z += a.z*b.z; acc[2].w += a.z*b.w;
        acc[3].x += a.w*b.x; acc[3].y += a.w*b.y; acc[3].z += a.w*b.z; acc[3].w += a.w*b.w;
    }
}

// ---------------- K1: hid = relu(inputs @ fc1_w.T + fc1_b) ----------------
__global__ __launch_bounds__(256, 2) void k_fc1(const float* __restrict__ in,
        const float* __restrict__ w, const float* __restrict__ b,
        float* __restrict__ hid){
    __shared__ float lin[8*OBSD];
    int at = blockIdx.y, ot = blockIdx.x, t = threadIdx.x;
    ((float4*)lin)[t] = ((const float4*)(in + at*8*OBSD))[t];
    __syncthreads();
    int ol = t & 63, g = t >> 6;
    int o = ot*64 + ol;
    const float4* w4 = (const float4*)(w + o*OBSD);
    const float4* la = (const float4*)(lin + (g*2)*OBSD);
    const float4* lb = (const float4*)(lin + (g*2+1)*OBSD);
    float4 a0 = {0,0,0,0}, a1 = {0,0,0,0};
    #pragma unroll
    for (int c = 0; c < OBSD/4; ++c){
        float4 wv = w4[c];
        fma4(a0, la[c], wv);
        fma4(a1, lb[c], wv);
    }
    float bb = b[o];
    int ag = at*8 + g*2;
    hid[ag*HIDD + o]     = fmaxf(hsum(a0) + bb, 0.f);
    hid[(ag+1)*HIDD + o] = fmaxf(hsum(a1) + bb, 0.f);
}

// ---------------- K2: qkv = hid @ in_proj_w.T + in_proj_b ----------------
__global__ __launch_bounds__(256, 2) void k_qkv(const float* __restrict__ hid,
        const float* __restrict__ w, const float* __restrict__ b,
        float* __restrict__ qkv){
    __shared__ float lin[8*HIDD];
    int at = blockIdx.y, ot = blockIdx.x, t = threadIdx.x;
    const float4* in4 = (const float4*)(hid + at*8*HIDD);
    ((float4*)lin)[t]       = in4[t];
    ((float4*)lin)[t + 256] = in4[t + 256];
    __syncthreads();
    int ol = t & 63, g = t >> 6;
    int o = ot*64 + ol;                       // 0..767
    const float4* w4 = (const float4*)(w + o*HIDD);
    const float4* la = (const float4*)(lin + (g*2)*HIDD);
    const float4* lb = (const float4*)(lin + (g*2+1)*HIDD);
    float4 a0 = {0,0,0,0}, a1 = {0,0,0,0};
    #pragma unroll 8
    for (int c = 0; c < HIDD/4; ++c){
        float4 wv = w4[c];
        fma4(a0, la[c], wv);
        fma4(a1, lb[c], wv);
    }
    float bb = b[o];
    int ag = at*8 + g*2;
    qkv[ag*768 + o]     = hsum(a0) + bb;
    qkv[(ag+1)*768 + o] = hsum(a1) + bb;
}

// ---------------- K3: blocks 0..63 scores S=QK^T/16 | 64..95 VW=V@ow^T | 96..2143 vfc2_w stream ----------------
__global__ __launch_bounds__(256, 2) void k_big(const float* __restrict__ qkv,
        const float* __restrict__ ow, const float* __restrict__ hid,
        const float* __restrict__ vw_w, float* __restrict__ S,
        float* __restrict__ VW, float* __restrict__ partial){
    __shared__ float As[32*68];
    __shared__ float Bs[32*68];
    int t = threadIdx.x;
    int bid = blockIdx.x;
    if (bid < 64){
        // ---- scores tile: S[i0+..64][j0+..64] = dot(Q_i, K_j) * 0.0625 ----
        int ti = bid >> 3, tj = bid & 7;
        int i0 = ti*64, j0 = tj*64;
        int tx = t & 15, ty = t >> 4;
        float4 acc[4] = {{0,0,0,0},{0,0,0,0},{0,0,0,0},{0,0,0,0}};
        for (int k0 = 0; k0 < 256; k0 += 32){
            __syncthreads();
            stage_rows(As, qkv, i0, 768, k0,       t);   // Q chunk
            stage_rows(Bs, qkv, j0, 768, 256 + k0, t);   // K chunk
            __syncthreads();
            tile_compute(As, Bs, tx, ty, acc);
        }
        #pragma unroll
        for (int r = 0; r < 4; ++r){
            float4 o;
            o.x = acc[r].x*0.0625f; o.y = acc[r].y*0.0625f;
            o.z = acc[r].z*0.0625f; o.w = acc[r].w*0.0625f;
            *(float4*)(S + (i0+ty*4+r)*512 + j0 + tx*4) = o;
        }
        return;
    }
    if (bid < 96){
        // ---- VW tile: VW[j0+..64][d0+..64] = dot(V_j, ow_d) ----
        int b2 = bid - 64;
        int ti = b2 >> 2, tj = b2 & 3;
        int j0 = ti*64, d0 = tj*64;
        int tx = t & 15, ty = t >> 4;
        float4 acc[4] = {{0,0,0,0},{0,0,0,0},{0,0,0,0},{0,0,0,0}};
        for (int k0 = 0; k0 < 256; k0 += 32){
            __syncthreads();
            stage_rows(As, qkv, j0, 768, 512 + k0, t);   // V chunk
            stage_rows(Bs, ow,  d0, 256, k0,       t);   // ow chunk
            __syncthreads();
            tile_compute(As, Bs, tx, ty, acc);
        }
        #pragma unroll
        for (int r = 0; r < 4; ++r)
            *(float4*)(VW + (j0+ty*4+r)*256 + d0 + tx*4) = acc[r];
        return;
    }
    // ---- vpart: 64KB chunk of one vfc2_w row, dot with flattened hid ----
    int id = bid - 96;                 // 0..2047
    int chunk = id & 7, o = id >> 3;
    const float4* h4 = (const float4*)hid;
    const float4* w4 = (const float4*)vw_w;
    long base  = (long)chunk*4096;     // float4 units
    long wbase = (long)o*32768 + base;
    float4 aa = {0,0,0,0}, ab = {0,0,0,0};
    #pragma unroll 4
    for (int it = 0; it < 8; ++it){    // two interleaved streams -> 2x load ILP
        fma4(aa, h4[base + it*256 + t],     w4[wbase + it*256 + t]);
        fma4(ab, h4[base + (it+8)*256 + t], w4[wbase + (it+8)*256 + t]);
    }
    float acc = hsum(aa) + hsum(ab);
    for (int off = 32; off; off >>= 1) acc += __shfl_xor(acc, off);
    int lane = t & 63, wid = t >> 6;
    if (lane == 0) As[wid] = acc;
    __syncthreads();
    if (t == 0) partial[o*8 + chunk] = As[0]+As[1]+As[2]+As[3];
}

// ---------------- K4: row softmax in-place on S, wave per row, grid 128 ----------------
__global__ __launch_bounds__(256, 2) void k_softmax(float* __restrict__ S){
    int t = threadIdx.x, w = t >> 6, ln = t & 63;
    float* row = S + (blockIdx.x*4 + w)*512;
    float v[8];
    float m = -1e30f;
    #pragma unroll
    for (int k = 0; k < 8; ++k){ v[k] = row[ln + k*64]; m = fmaxf(m, v[k]); }
    for (int off = 32; off; off >>= 1) m = fmaxf(m, __shfl_xor(m, off));
    float s = 0.f;
    #pragma unroll
    for (int k = 0; k < 8; ++k){ v[k] = expf(v[k] - m); s += v[k]; }
    for (int off = 32; off; off >>= 1) s += __shfl_xor(s, off);
    float inv = 1.f / s;
    #pragma unroll
    for (int k = 0; k < 8; ++k) row[ln + k*64] = v[k]*inv;
}

// ---------------- K5: h = P @ VW + ob, grid 32 (8 i-tiles x 4 d-tiles) ----------------
__global__ __launch_bounds__(256, 2) void k_h(const float* __restrict__ P,
        const float* __restrict__ VW, const float* __restrict__ ob,
        float* __restrict__ hout){
    __shared__ float As[32*68];
    __shared__ float Bs[32*68];
    int bid = blockIdx.x;
    int ti = bid >> 2, tj = bid & 3;
    int i0 = ti*64, d0 = tj*64;
    int t = threadIdx.x, tx = t & 15, ty = t >> 4;
    float4 acc[4] = {{0,0,0,0},{0,0,0,0},{0,0,0,0},{0,0,0,0}};
    for (int k0 = 0; k0 < 512; k0 += 32){
        __syncthreads();
        stage_rows(As, P, i0, 512, k0, t);               // P chunk (transposed)
        // B is K-major already: Bs[kk][d] = VW[(k0+kk)*256 + d0+d]
        #pragma unroll
        for (int half = 0; half < 2; ++half){
            int idx = half*256 + t;
            int kkr = idx >> 4, c4 = idx & 15;
            *(float4*)(Bs + kkr*68 + c4*4) = *(const float4*)(VW + (k0+kkr)*256 + d0 + c4*4);
        }
        __syncthreads();
        tile_compute(As, Bs, tx, ty, acc);
    }
    float4 bb = *(const float4*)(ob + d0 + tx*4);
    #pragma unroll
    for (int r = 0; r < 4; ++r){
        float4 o;
        o.x = acc[r].x + bb.x; o.y = acc[r].y + bb.y;
        o.z = acc[r].z + bb.z; o.w = acc[r].w + bb.w;
        *(float4*)(hout + (i0+ty*4+r)*256 + d0 + tx*4) = o;
    }
}

// ---------------- K6: A/B projections (blocks 0..511) || value finish (block 512) ----------------
__global__ __launch_bounds__(256, 2) void k_ab_value(const float* __restrict__ hin,
        const float* __restrict__ w2, const float* __restrict__ b2,
        const float* __restrict__ partial, const float* __restrict__ vb,
        const float* __restrict__ v3w, const float* __restrict__ v3b,
        float* __restrict__ A, float* __restrict__ B, float* __restrict__ value){
    int t = threadIdx.x;
    if (blockIdx.x == 512){
        float s = vb[t];
        #pragma unroll
        for (int c = 0; c < 8; ++c) s += partial[t*8 + c];
        s = fmaxf(s, 0.f) * v3w[t];
        for (int off = 32; off; off >>= 1) s += __shfl_xor(s, off);
        __shared__ float redv[4];
        int lane = t & 63, wid = t >> 6;
        if (lane == 0) redv[wid] = s;
        __syncthreads();
        if (t == 0) value[0] = redv[0]+redv[1]+redv[2]+redv[3] + v3b[0];
        return;
    }
    __shared__ float lin[8*HIDD];
    int id = blockIdx.x, at = id >> 3, ot = id & 7;
    const float4* in4 = (const float4*)(hin + at*8*HIDD);
    ((float4*)lin)[t]       = in4[t];
    ((float4*)lin)[t + 256] = in4[t + 256];
    __syncthreads();
    int ol = t & 63, g = t >> 6;
    int o2 = ot*64 + ol;                   // 0..511
    bool isA = o2 < HIDD;
    int o = isA ? o2 : o2 - HIDD;
    const float4* w4 = (const float4*)(w2 + o*512 + (isA ? 0 : HIDD));
    const float4* la = (const float4*)(lin + (g*2)*HIDD);
    const float4* lb = (const float4*)(lin + (g*2+1)*HIDD);
    float4 acc0 = {0,0,0,0}, acc1 = {0,0,0,0};
    #pragma unroll 8
    for (int c = 0; c < HIDD/4; ++c){
        float4 wv = w4[c];
        fma4(acc0, la[c], wv);
        fma4(acc1, lb[c], wv);
    }
    int a0 = at*8 + g*2;
    float* dst = isA ? A : B;
    float bb = isA ? b2[o] : 0.f;          // fold fc2_b into A
    dst[a0*HIDD + o]     = hsum(acc0) + bb;
    dst[(a0+1)*HIDD + o] = hsum(acc1) + bb;
}

// ---------------- K7: per-pair x=relu(A[i]+B[j]); out = [sigmoid(wd.x+bd), 1-., value] ----------------
__global__ __launch_bounds__(256, 2) void k_pairs(const float* __restrict__ A,
        const float* __restrict__ B, const float* __restrict__ w3,
        const float* __restrict__ b3, const float* __restrict__ value,
        float* __restrict__ out){
    int ti = blockIdx.x, tj = blockIdx.y;
    if (tj < ti) return;                   // strictly-lower tiles have no pairs
    __shared__ float la[16*260], lb[16*260], lw[256];
    int t = threadIdx.x;
    #pragma unroll
    for (int l = 0; l < 4; ++l){
        int idx = l*256 + t;
        int r = idx >> 6, c4 = idx & 63;
        ((float4*)la)[r*65 + c4] = ((const float4*)A)[(ti*16 + r)*64 + c4];
        ((float4*)lb)[r*65 + c4] = ((const float4*)B)[(tj*16 + r)*64 + c4];
    }
    lw[t] = w3[t] - w3[256 + t];           // fc3_w[0]-fc3_w[1]
    __syncthreads();
    float val = value[0];
    float bd  = b3[0] - b3[1];
    int il = t >> 4, jl = t & 15;
    int i = ti*16 + il, j = tj*16 + jl;
    if (j > i){
        const float4* a4 = (const float4*)(la + il*260);
        const float4* b4 = (const float4*)(lb + jl*260);
        const float4* w4 = (const float4*)lw;
        float4 acc = {0,0,0,0};
        #pragma unroll 8
        for (int c = 0; c < 64; ++c){
            float4 aa = a4[c], bb = b4[c], wv = w4[c];
            acc.x += fmaxf(aa.x + bb.x, 0.f)*wv.x;
            acc.y += fmaxf(aa.y + bb.y, 0.f)*wv.y;
            acc.z += fmaxf(aa.z + bb.z, 0.f)*wv.z;
            acc.w += fmaxf(aa.w + bb.w, 0.f)*wv.w;
        }
        float z = hsum(acc) + bd;
        float o0 = 1.f/(1.f + expf(-z));
        int p = i*511 - (i*(i-1))/2 + (j - i - 1);
        out[3*p]   = o0;
        out[3*p+1] = 1.f - o0;
        out[3*p+2] = val;
    }
}

extern "C" void kernel_launch(void* const* d_in, const int* in_sizes, int n_in,
                              void* d_out, int out_size, void* d_ws, size_t ws_size,
                              hipStream_t stream){
    const float* inputs = (const float*)d_in[0];
    const float* fc1_w  = (const float*)d_in[1];
    const float* fc1_b  = (const float*)d_in[2];
    const float* inp_w  = (const float*)d_in[3];
    const float* inp_b  = (const float*)d_in[4];
    const float* outp_w = (const float*)d_in[5];
    const float* outp_b = (const float*)d_in[6];
    const float* fc2_w  = (const float*)d_in[7];
    const float* fc2_b  = (const float*)d_in[8];
    const float* fc3_w  = (const float*)d_in[9];
    const float* fc3_b  = (const float*)d_in[10];
    const float* vfc2_w = (const float*)d_in[11];
    const float* vfc2_b = (const float*)d_in[12];
    const float* vfc3_w = (const float*)d_in[13];
    const float* vfc3_b = (const float*)d_in[14];
    float* out = (float*)d_out;
    float* ws  = (float*)d_ws;
    // ws layout (floats): total ~1.19M (~4.8 MB)
    float* hid     = ws;              // 512*256   = 131072
    float* qkv     = ws + 131072;     // 512*768   = 393216
    float* S       = ws + 524288;     // 512*512   = 262144  (scores -> softmax in place)
    float* VW      = ws + 786432;     // 512*256   = 131072
    float* h       = ws + 917504;     // 512*256   = 131072
    float* A       = ws + 1048576;    // 512*256   = 131072
    float* B       = ws + 1179648;    // 512*256   = 131072
    float* partial = ws + 1310720;    // 256*8     = 2048
    float* value   = ws + 1312768;    // 1

    k_fc1     <<<dim3(4, 64),  256, 0, stream>>>(inputs, fc1_w, fc1_b, hid);
    k_qkv     <<<dim3(12, 64), 256, 0, stream>>>(hid, inp_w, inp_b, qkv);
    k_big     <<<dim3(2144),   256, 0, stream>>>(qkv, outp_w, hid, vfc2_w, S, VW, partial);
    k_softmax <<<dim3(128),    256, 0, stream>>>(S);
    k_h       <<<dim3(32),     256, 0, stream>>>(S, VW, outp_b, h);
    k_ab_value<<<dim3(513),    256, 0, stream>>>(h, fc2_w, fc2_b, partial, vfc2_b, vfc3_w, vfc3_b, A, B, value);
    k_pairs   <<<dim3(32, 32), 256, 0, stream>>>(A, B, fc3_w, fc3_b, value, out);
}